// Round 1
// baseline (223.352 us; speedup 1.0000x reference)
//
#include <hip/hip_runtime.h>
#include <math.h>

#define T_ 32
#define B_ 16
#define V_ 30000
#define D_ 300
#define DQKV_ 150
#define K_ 10
#define G_ 32
#define N_ 320      // K*G
#define S_ 25000
#define NTHREADS 256

__device__ __forceinline__ bool better(float av, int ai, float bv, int bi) {
    // ranks (av,ai) strictly before (bv,bi): higher value, ties -> lower index
    return (av > bv) || (av == bv && ai < bi);
}

__global__ __launch_bounds__(NTHREADS) void selfatt_kernel(
    const float* __restrict__ pred,   // [T*B, V]
    const float* __restrict__ lc,     // [T*B, D]
    const float* __restrict__ SC,     // [S, D]
    const float* __restrict__ Wq,     // [D, DQKV]
    const float* __restrict__ Wk,     // [D, DQKV]
    const int*   __restrict__ nbt,    // [V, G] int32
    float* __restrict__ out)          // [T*B, S]
{
    const int row  = blockIdx.x;
    const int tid  = threadIdx.x;
    const int lane = tid & 63;
    const int wave = tid >> 6;

    __shared__ float cv[NTHREADS * K_];
    __shared__ int   ci[NTHREADS * K_];
    __shared__ int   topg[K_];
    __shared__ float lcs[D_];
    __shared__ float qs[DQKV_];
    __shared__ float qks[D_];
    __shared__ int   nidx[N_];
    __shared__ float lg[N_];
    __shared__ float wredv[4];
    __shared__ int   wredi[4];
    __shared__ int   sbesti;
    __shared__ float smax, slogsum;

    float* outrow = out + (size_t)row * S_;

    // ---- Phase 0: fill output row with log(EPS) (overlaps with topk scan) ----
    const float FILL = -18.420680743952367f;   // log(1e-8) in f32
    {
        float4 f4 = make_float4(FILL, FILL, FILL, FILL);
        float4* orow4 = (float4*)outrow;
        #pragma unroll 4
        for (int i = tid; i < S_ / 4; i += NTHREADS) orow4[i] = f4;
    }

    // ---- Phase 1: per-thread top-10 over strided chunk of the 30000 logits ----
    float tv[K_];
    int   ti[K_];
    #pragma unroll
    for (int s = 0; s < K_; ++s) { tv[s] = -INFINITY; ti[s] = 0x7fffffff; }
    {
        const float* prow = pred + (size_t)row * V_;
        for (int i = tid; i < V_; i += NTHREADS) {
            float val = prow[i];
            if (better(val, i, tv[K_-1], ti[K_-1])) {
                tv[K_-1] = val; ti[K_-1] = i;
                #pragma unroll
                for (int s = K_-1; s > 0; --s) {
                    if (better(tv[s], ti[s], tv[s-1], ti[s-1])) {
                        float a = tv[s]; tv[s] = tv[s-1]; tv[s-1] = a;
                        int   b = ti[s]; ti[s] = ti[s-1]; ti[s-1] = b;
                    }
                }
            }
        }
    }
    #pragma unroll
    for (int s = 0; s < K_; ++s) { cv[tid*K_ + s] = tv[s]; ci[tid*K_ + s] = ti[s]; }
    __syncthreads();

    // ---- Phase 2: block top-10 via 10 argmax passes over 2560 candidates ----
    for (int p = 0; p < K_; ++p) {
        float bv = -INFINITY; int bi = 0x7fffffff;
        #pragma unroll
        for (int s = 0; s < K_; ++s) {
            float vv = cv[tid*K_ + s]; int ii = ci[tid*K_ + s];
            if (better(vv, ii, bv, bi)) { bv = vv; bi = ii; }
        }
        #pragma unroll
        for (int off = 32; off > 0; off >>= 1) {
            float ov = __shfl_xor(bv, off, 64);
            int   oi = __shfl_xor(bi, off, 64);
            if (better(ov, oi, bv, bi)) { bv = ov; bi = oi; }
        }
        if (lane == 0) { wredv[wave] = bv; wredi[wave] = bi; }
        __syncthreads();
        if (tid == 0) {
            float xv = wredv[0]; int xi = wredi[0];
            #pragma unroll
            for (int w = 1; w < 4; ++w)
                if (better(wredv[w], wredi[w], xv, xi)) { xv = wredv[w]; xi = wredi[w]; }
            sbesti = xi;
            topg[p] = xi;
        }
        __syncthreads();
        int win = sbesti;
        #pragma unroll
        for (int s = 0; s < K_; ++s)
            if (ci[tid*K_ + s] == win) cv[tid*K_ + s] = -INFINITY;
        __syncthreads();
    }

    // ---- Phase 3: gather neighbour sense ids; load location-context row ----
    for (int d = tid; d < D_; d += NTHREADS) lcs[d] = lc[(size_t)row * D_ + d];
    for (int n = tid; n < N_; n += NTHREADS) {
        int g = topg[n >> 5];                 // n/32 -> which top-k global
        nidx[n] = nbt[g * G_ + (n & 31)];
    }
    __syncthreads();

    // ---- Phase 4: q = lcs @ Wq  [150] ----
    if (tid < DQKV_) {
        float acc = 0.f;
        for (int d = 0; d < D_; ++d) acc += lcs[d] * Wq[d * DQKV_ + tid];
        qs[tid] = acc;
    }
    __syncthreads();

    // ---- Phase 5: qk[d] = Wk[d,:] . q  [300] ----
    for (int d = tid; d < D_; d += NTHREADS) {
        float acc = 0.f;
        for (int j = 0; j < DQKV_; ++j) acc += Wk[d * DQKV_ + j] * qs[j];
        qks[d] = acc;
    }
    __syncthreads();

    // ---- Phase 6: logits[n] = (qk . SC[nidx[n]]) / sqrt(150) ----
    const float ISC = 0.08164965809277260327f;   // 1/sqrt(150)
    for (int n = tid; n < N_; n += NTHREADS) {
        const float* sc = SC + (size_t)nidx[n] * D_;
        float acc = 0.f;
        for (int d = 0; d < D_; ++d) acc += qks[d] * sc[d];
        lg[n] = acc * ISC;
    }
    __syncthreads();

    // ---- Phase 7: softmax stats over the 320 logits ----
    float m = -INFINITY;
    for (int n = tid; n < N_; n += NTHREADS) m = fmaxf(m, lg[n]);
    #pragma unroll
    for (int off = 32; off > 0; off >>= 1) m = fmaxf(m, __shfl_xor(m, off, 64));
    if (lane == 0) wredv[wave] = m;
    __syncthreads();
    if (tid == 0) smax = fmaxf(fmaxf(wredv[0], wredv[1]), fmaxf(wredv[2], wredv[3]));
    __syncthreads();
    m = smax;

    float ssum = 0.f;
    for (int n = tid; n < N_; n += NTHREADS) ssum += expf(lg[n] - m);
    #pragma unroll
    for (int off = 32; off > 0; off >>= 1) ssum += __shfl_xor(ssum, off, 64);
    if (lane == 0) wredv[wave] = ssum;
    __syncthreads();
    if (tid == 0) slogsum = logf(wredv[0] + wredv[1] + wredv[2] + wredv[3]);
    __syncthreads();
    const float lsum = slogsum;

    // ---- Phase 8: scatter log-probs, numpy last-write-wins on duplicates ----
    // (fill from Phase 0 is ordered before this by the syncthreads above;
    //  same block owns the whole row, so no cross-block hazard)
    for (int n = tid; n < N_; n += NTHREADS) {
        int sidx = nidx[n];
        bool last = true;
        for (int n2 = n + 1; n2 < N_; ++n2)
            if (nidx[n2] == sidx) { last = false; break; }
        if (last) outrow[sidx] = (lg[n] - m) - lsum;
    }
}

extern "C" void kernel_launch(void* const* d_in, const int* in_sizes, int n_in,
                              void* d_out, int out_size, void* d_ws, size_t ws_size,
                              hipStream_t stream) {
    const float* pred = (const float*)d_in[0];
    const float* lc   = (const float*)d_in[1];
    const float* SC   = (const float*)d_in[2];
    const float* Wq   = (const float*)d_in[3];
    const float* Wk   = (const float*)d_in[4];
    const int*   nbt  = (const int*)d_in[5];
    float* out = (float*)d_out;

    selfatt_kernel<<<dim3(T_ * B_), dim3(NTHREADS), 0, stream>>>(
        pred, lc, SC, Wq, Wk, nbt, out);
}

// Round 2
// 207.135 us; speedup vs baseline: 1.0783x; 1.0783x over previous
//
#include <hip/hip_runtime.h>
#include <math.h>

#define T_ 32
#define B_ 16
#define V_ 30000
#define D_ 300
#define DQKV_ 150
#define K_ 10
#define G_ 32
#define N_ 320      // K*G
#define S_ 25000
#define NT 512
#define NWAVES (NT / 64)

__device__ __forceinline__ bool better(float av, int ai, float bv, int bi) {
    // ranks (av,ai) strictly before (bv,bi): higher value, ties -> lower index
    return (av > bv) || (av == bv && ai < bi);
}

__global__ __launch_bounds__(NT) void selfatt_kernel(
    const float* __restrict__ pred,   // [T*B, V]
    const float* __restrict__ lc,     // [T*B, D]
    const float* __restrict__ SC,     // [S, D]
    const float* __restrict__ Wq,     // [D, DQKV]
    const float* __restrict__ Wk,     // [D, DQKV]
    const int*   __restrict__ nbt,    // [V, G] int32
    float* __restrict__ out)          // [T*B, S]
{
    const int row  = blockIdx.x;
    const int tid  = threadIdx.x;
    const int lane = tid & 63;
    const int wave = tid >> 6;

    __shared__ float lcs[D_];
    __shared__ float qs[DQKV_];
    __shared__ __align__(16) float qks[D_];
    __shared__ int   nidx[N_];
    __shared__ float lg[N_];
    __shared__ float wredv[NWAVES];
    __shared__ int   wredi[NWAVES];
    __shared__ int   sbi;
    __shared__ int   topg[K_];
    __shared__ float smax, slogsum;

    float* outrow = out + (size_t)row * S_;

    // ---- Phase 0: fill output row with log(EPS), vectorized ----
    const float FILL = -18.420680743952367f;   // log(1e-8)
    {
        float4 f4 = make_float4(FILL, FILL, FILL, FILL);
        float4* orow4 = (float4*)outrow;
        for (int i = tid; i < S_ / 4; i += NT) orow4[i] = f4;   // 6250 float4
    }

    // ---- Phase 1: per-thread top-10, float4 scan over the 30000 logits ----
    float tv[K_];
    int   ti[K_];
    #pragma unroll
    for (int s = 0; s < K_; ++s) { tv[s] = -INFINITY; ti[s] = 0x7fffffff; }
    {
        const float4* prow4 = (const float4*)(pred + (size_t)row * V_);
        for (int i = tid; i < V_ / 4; i += NT) {     // 7500 float4
            float4 v = prow4[i];
            float vals[4] = {v.x, v.y, v.z, v.w};
            #pragma unroll
            for (int c = 0; c < 4; ++c) {
                float val = vals[c];
                int   idx = i * 4 + c;
                if (better(val, idx, tv[K_-1], ti[K_-1])) {
                    tv[K_-1] = val; ti[K_-1] = idx;
                    #pragma unroll
                    for (int s = K_-1; s > 0; --s) {
                        if (better(tv[s], ti[s], tv[s-1], ti[s-1])) {
                            float a = tv[s]; tv[s] = tv[s-1]; tv[s-1] = a;
                            int   b = ti[s]; ti[s] = ti[s-1]; ti[s-1] = b;
                        }
                    }
                }
            }
        }
    }

    // ---- Phase 2: block top-10 via 10 register-argmax passes (no LDS cands) ----
    for (int p = 0; p < K_; ++p) {
        float bv = tv[0]; int bi = ti[0];
        #pragma unroll
        for (int s = 1; s < K_; ++s)
            if (better(tv[s], ti[s], bv, bi)) { bv = tv[s]; bi = ti[s]; }
        #pragma unroll
        for (int off = 32; off > 0; off >>= 1) {
            float ov = __shfl_xor(bv, off, 64);
            int   oi = __shfl_xor(bi, off, 64);
            if (better(ov, oi, bv, bi)) { bv = ov; bi = oi; }
        }
        if (lane == 0) { wredv[wave] = bv; wredi[wave] = bi; }
        __syncthreads();
        if (tid == 0) {
            float xv = wredv[0]; int xi = wredi[0];
            #pragma unroll
            for (int w = 1; w < NWAVES; ++w)
                if (better(wredv[w], wredi[w], xv, xi)) { xv = wredv[w]; xi = wredi[w]; }
            sbi = xi;
            topg[p] = xi;
        }
        __syncthreads();
        int win = sbi;
        #pragma unroll
        for (int s = 0; s < K_; ++s)
            if (ti[s] == win) tv[s] = -INFINITY;
    }

    // ---- Phase 3: gather neighbour sense ids; load location-context row ----
    for (int d = tid; d < D_; d += NT) lcs[d] = lc[(size_t)row * D_ + d];
    for (int n = tid; n < N_; n += NT) {
        int g = topg[n >> 5];
        nidx[n] = nbt[g * G_ + (n & 31)];
    }
    __syncthreads();

    // ---- Phase 4: q = lcs @ Wq  [150], 2 threads per output ----
    if (tid < 2 * DQKV_) {        // 300 threads
        int j = tid >> 1, h = tid & 1;
        float acc = 0.f;
        int d0 = h * 150;
        for (int d = d0; d < d0 + 150; ++d) acc += lcs[d] * Wq[d * DQKV_ + j];
        acc += __shfl_xor(acc, 1, 64);
        if (h == 0) qs[j] = acc;
    }
    __syncthreads();

    // ---- Phase 5: qk[d] = Wk[d,:] . q  [300], 2 threads per output ----
    if (tid < 2 * D_) {           // 600 > NT? no: 600 > 512 -> loop
        // handled below with strided loop instead
    }
    for (int t = tid; t < 2 * D_; t += NT) {
        int d = t >> 1, h = t & 1;
        const float* wrow = Wk + d * DQKV_;
        float acc = 0.f;
        int j0 = h * 75;
        for (int j = j0; j < j0 + 75; ++j) acc += wrow[j] * qs[j];
        acc += __shfl_xor(acc, 1, 64);
        if (h == 0) qks[d] = acc;
    }
    __syncthreads();

    // ---- Phase 6: logits[n] = (qk . SC[nidx[n]]) / sqrt(150), float4 dots ----
    const float ISC = 0.08164965809277260327f;   // 1/sqrt(150)
    for (int t = tid; t < 2 * N_; t += NT) {      // 640 lanes of work
        int n = t >> 1, h = t & 1;
        const float4* sc4 = (const float4*)(SC + (size_t)nidx[n] * D_);
        const float4* q4  = (const float4*)qks;
        float acc = 0.f;
        int d0 = h ? 38 : 0, d1 = h ? 75 : 38;    // 75 float4 per row
        for (int d = d0; d < d1; ++d) {
            float4 a = sc4[d], b = q4[d];
            acc += a.x * b.x + a.y * b.y + a.z * b.z + a.w * b.w;
        }
        acc += __shfl_xor(acc, 1, 64);
        if (h == 0) lg[n] = acc * ISC;
    }
    __syncthreads();

    // ---- Phase 7: softmax stats over the 320 logits ----
    float m = -INFINITY;
    for (int n = tid; n < N_; n += NT) m = fmaxf(m, lg[n]);
    #pragma unroll
    for (int off = 32; off > 0; off >>= 1) m = fmaxf(m, __shfl_xor(m, off, 64));
    if (lane == 0) wredv[wave] = m;
    __syncthreads();
    if (tid == 0) {
        float xm = wredv[0];
        #pragma unroll
        for (int w = 1; w < NWAVES; ++w) xm = fmaxf(xm, wredv[w]);
        smax = xm;
    }
    __syncthreads();
    m = smax;

    float ssum = 0.f;
    for (int n = tid; n < N_; n += NT) ssum += expf(lg[n] - m);
    #pragma unroll
    for (int off = 32; off > 0; off >>= 1) ssum += __shfl_xor(ssum, off, 64);
    if (lane == 0) wredv[wave] = ssum;
    __syncthreads();
    if (tid == 0) {
        float xs = 0.f;
        #pragma unroll
        for (int w = 0; w < NWAVES; ++w) xs += wredv[w];
        slogsum = logf(xs);
    }
    __syncthreads();
    const float lsum = slogsum;

    // ---- Phase 8: scatter log-probs, numpy last-write-wins on duplicates ----
    for (int n = tid; n < N_; n += NT) {
        int sidx = nidx[n];
        bool last = true;
        for (int n2 = n + 1; n2 < N_; ++n2)
            if (nidx[n2] == sidx) { last = false; break; }
        if (last) outrow[sidx] = (lg[n] - m) - lsum;
    }
}

extern "C" void kernel_launch(void* const* d_in, const int* in_sizes, int n_in,
                              void* d_out, int out_size, void* d_ws, size_t ws_size,
                              hipStream_t stream) {
    const float* pred = (const float*)d_in[0];
    const float* lc   = (const float*)d_in[1];
    const float* SC   = (const float*)d_in[2];
    const float* Wq   = (const float*)d_in[3];
    const float* Wk   = (const float*)d_in[4];
    const int*   nbt  = (const int*)d_in[5];
    float* out = (float*)d_out;

    selfatt_kernel<<<dim3(T_ * B_), dim3(NT), 0, stream>>>(
        pred, lc, SC, Wq, Wk, nbt, out);
}